// Round 6
// baseline (251.354 us; speedup 1.0000x reference)
//
#include <hip/hip_runtime.h>

#define HID 128
#define BM 128
#define BK 32

typedef unsigned short ushort_t;
typedef unsigned int uint_t;

__device__ __forceinline__ float bflo(uint_t u) { return __uint_as_float(u << 16); }
__device__ __forceinline__ float bfhi(uint_t u) { return __uint_as_float(u & 0xFFFF0000u); }
__device__ __forceinline__ uint_t f2bf(float f) {
    uint_t x = __float_as_uint(f);
    return (x + 0x7FFFu + ((x >> 16) & 1u)) >> 16;   // RNE
}

// ---------------------------------------------------------------------------
// Detect whether edge_index was materialized as int64 (odd 32-bit words all 0)
// or int32. Values are node ids in [0, 50000) so the high word of int64 is 0.
// ---------------------------------------------------------------------------
__global__ void detect_idx64(const int* __restrict__ E, int* __restrict__ flag) {
    int l = threadIdx.x;                       // 64 threads
    int v = E[2 * l + 1] | E[2 * (l + 64) + 1];
    unsigned long long b = __ballot(v != 0);
    if (l == 0) flag[0] = (b == 0ull) ? 1 : 0;
}

__device__ __forceinline__ int load_idx(const int* __restrict__ E, int pos, bool is64) {
    return is64 ? E[2 * pos] : E[pos];
}

// ---------------------------------------------------------------------------
// Register-blocked SGEMM: T = relu(X @ W + B)  (X: n x 128, W: 128 x 128)
// Block: 256 threads (16x16), tile BM=128 rows, BK=32 k-slice, 8x8 micro-tile.
// mode 0: write full T rows as bf16.  mode 1: fuse dot with Wf, write S only.
// ---------------------------------------------------------------------------
__global__ __launch_bounds__(256, 2) void mlp_gemm(
    const float* __restrict__ X, const float* __restrict__ W,
    const float* __restrict__ Bv, const float* __restrict__ Wf,
    ushort_t* __restrict__ T, float* __restrict__ S, int n, int mode)
{
    __shared__ float Xs[BK][BM + 1];     // transposed X tile, +1 pad
    __shared__ float Wsh[BK][HID];       // W k-slice, natural layout

    const int t  = threadIdx.x;
    const int tn = t & 15;               // column-group 0..15 (8 cols each)
    const int tm = t >> 4;               // row-group 0..15 (8 rows each)
    const int base = blockIdx.x * BM;

    float acc[8][8];
#pragma unroll
    for (int r = 0; r < 8; ++r)
#pragma unroll
        for (int c = 0; c < 8; ++c) acc[r][c] = 0.f;

    for (int kb = 0; kb < HID; kb += BK) {
#pragma unroll
        for (int pass = 0; pass < 4; ++pass) {
            const int row = pass * 32 + (t >> 3);
            const int kc  = (t & 7) * 4;
            float4 v = {0.f, 0.f, 0.f, 0.f};
            const int gr = base + row;
            if (gr < n) v = *(const float4*)(X + (size_t)gr * HID + kb + kc);
            Xs[kc + 0][row] = v.x;
            Xs[kc + 1][row] = v.y;
            Xs[kc + 2][row] = v.z;
            Xs[kc + 3][row] = v.w;
        }
#pragma unroll
        for (int pass = 0; pass < 4; ++pass) {
            const int kr = pass * 8 + (t >> 5);
            const int nc = (t & 31) * 4;
            *(float4*)(&Wsh[kr][nc]) =
                *(const float4*)(W + (size_t)(kb + kr) * HID + nc);
        }
        __syncthreads();

#pragma unroll
        for (int k = 0; k < BK; ++k) {
            float xr[8], wc[8];
            *(float4*)&xr[0] = *(const float4*)&Xs[k][tm * 8];
            *(float4*)&xr[4] = *(const float4*)&Xs[k][tm * 8 + 4];
            *(float4*)&wc[0] = *(const float4*)&Wsh[k][tn * 8];
            *(float4*)&wc[4] = *(const float4*)&Wsh[k][tn * 8 + 4];
#pragma unroll
            for (int r = 0; r < 8; ++r)
#pragma unroll
                for (int c = 0; c < 8; ++c)
                    acc[r][c] = fmaf(xr[r], wc[c], acc[r][c]);
        }
        __syncthreads();
    }

    float bv[8];
    *(float4*)&bv[0] = *(const float4*)(Bv + tn * 8);
    *(float4*)&bv[4] = *(const float4*)(Bv + tn * 8 + 4);

    if (mode == 0) {
#pragma unroll
        for (int r = 0; r < 8; ++r) {
            const int gr = base + tm * 8 + r;
            if (gr >= n) break;
            uint_t w[4];
#pragma unroll
            for (int c = 0; c < 4; ++c) {
                const float lo = fmaxf(acc[r][2 * c]     + bv[2 * c],     0.f);
                const float hi = fmaxf(acc[r][2 * c + 1] + bv[2 * c + 1], 0.f);
                w[c] = f2bf(lo) | (f2bf(hi) << 16);
            }
            *(uint4*)(T + (size_t)gr * HID + tn * 8) = *(uint4*)&w[0];
        }
    } else {
        float wf[8];
        *(float4*)&wf[0] = *(const float4*)(Wf + tn * 8);
        *(float4*)&wf[4] = *(const float4*)(Wf + tn * 8 + 4);
        float p[8];
#pragma unroll
        for (int r = 0; r < 8; ++r) {
            float s = 0.f;
#pragma unroll
            for (int c = 0; c < 8; ++c)
                s += fmaxf(acc[r][c] + bv[c], 0.f) * wf[c];
            p[r] = s;
        }
#pragma unroll
        for (int m = 1; m <= 8; m <<= 1)
#pragma unroll
            for (int r = 0; r < 8; ++r) p[r] += __shfl_xor(p[r], m);
        if (tn == 0) {
#pragma unroll
            for (int r = 0; r < 8; ++r) {
                const int gr = base + tm * 8 + r;
                if (gr < n) S[gr] = p[r];
            }
        }
    }
}

// ---------------------------------------------------------------------------
// CSR build: histogram of dst, hierarchical scan, permute src into dst order.
// ---------------------------------------------------------------------------
__global__ __launch_bounds__(256) void hist_dst(
    const int* __restrict__ E, const int* __restrict__ flag,
    int* __restrict__ cnt, int n_edges, int n_nodes)
{
    const bool is64 = (flag[0] != 0);
    const int t  = blockIdx.x * blockDim.x + threadIdx.x;
    const int nt = gridDim.x * blockDim.x;
    for (int e = t; e < n_edges; e += nt) {
        const int dst = load_idx(E, n_edges + e, is64);
        if ((unsigned)dst < (unsigned)n_nodes) atomicAdd(&cnt[dst], 1);
    }
}

// per-256-chunk exclusive scan; block sum out
__global__ __launch_bounds__(256) void scan_blk(
    const int* __restrict__ cnt, int* __restrict__ offs,
    int* __restrict__ blockSum, int n)
{
    __shared__ int sd[256];
    const int t = threadIdx.x;
    const int i = blockIdx.x * 256 + t;
    const int v = (i < n) ? cnt[i] : 0;
    sd[t] = v;
    __syncthreads();
    for (int d = 1; d < 256; d <<= 1) {
        const int u = (t >= d) ? sd[t - d] : 0;
        __syncthreads();
        sd[t] += u;
        __syncthreads();
    }
    if (i < n) offs[i] = sd[t] - v;          // local exclusive
    if (t == 255) blockSum[blockIdx.x] = sd[255];
}

// scan the (<=256*chunk) block sums in one small block; writes offs[n]=total
__global__ __launch_bounds__(256) void scan_top(
    int* __restrict__ blockSum, int* __restrict__ offs, int nb, int n)
{
    __shared__ int sd[256];
    const int t = threadIdx.x;
    const int chunk = (nb + 255) / 256;
    const int lo = t * chunk;
    const int hi = min(lo + chunk, nb);
    int s = 0;
    for (int i = lo; i < hi; ++i) s += blockSum[i];
    sd[t] = s;
    __syncthreads();
    for (int d = 1; d < 256; d <<= 1) {
        const int u = (t >= d) ? sd[t - d] : 0;
        __syncthreads();
        sd[t] += u;
        __syncthreads();
    }
    int run = sd[t] - s;                      // exclusive base of this chunk
    for (int i = lo; i < hi; ++i) {
        const int c = blockSum[i];
        blockSum[i] = run;                    // becomes block base
        run += c;
    }
    if (t == 255) offs[n] = sd[255];
}

__global__ __launch_bounds__(256) void scan_add(
    int* __restrict__ offs, int* __restrict__ pos,
    const int* __restrict__ blockSum, int n)
{
    const int i = blockIdx.x * 256 + threadIdx.x;
    if (i < n) {
        const int o = offs[i] + blockSum[blockIdx.x];
        offs[i] = o;
        pos[i]  = o;
    }
}

__global__ __launch_bounds__(256) void build_perm(
    const int* __restrict__ E, const int* __restrict__ flag,
    int* __restrict__ pos, int* __restrict__ srcSorted, int n_edges, int n_nodes)
{
    const bool is64 = (flag[0] != 0);
    const int t  = blockIdx.x * blockDim.x + threadIdx.x;
    const int nt = gridDim.x * blockDim.x;
    for (int e = t; e < n_edges; e += nt) {
        const int src = load_idx(E, e, is64);
        const int dst = load_idx(E, n_edges + e, is64);
        if ((unsigned)src >= (unsigned)n_nodes || (unsigned)dst >= (unsigned)n_nodes) continue;
        const int p = atomicAdd(&pos[dst], 1);
        // non-temporal: bypass local-L2 line ownership -> no cross-XCD
        // line ping-pong on the randomly scattered 4B stores
        __builtin_nontemporal_store(src, srcSorted + p);
    }
}

// ---------------------------------------------------------------------------
// Gather-reduce (layer 1): H[node] = sum over edges(dst==node) of T[src].
// One 32-lane group per node, lane owns 4 features (bf16 in T, fp32 acc).
// ---------------------------------------------------------------------------
__global__ __launch_bounds__(256) void gather_vec(
    const ushort_t* __restrict__ T, const int* __restrict__ offs,
    const int* __restrict__ srcSorted, float* __restrict__ H, int n_nodes)
{
    const int l32  = threadIdx.x & 31;
    const int j0   = l32 * 4;
    const int grp  = (int)((blockIdx.x * blockDim.x + threadIdx.x) >> 5);
    const int ngrp = (int)((gridDim.x * blockDim.x) >> 5);
    for (int node = grp; node < n_nodes; node += ngrp) {
        const int k0 = offs[node];
        const int k1 = offs[node + 1];
        float4 acc = {0.f, 0.f, 0.f, 0.f};
        for (int k = k0; k < k1; ++k) {
            const int s = srcSorted[k];
            const uint2 u = *(const uint2*)(T + (size_t)s * HID + j0);
            acc.x += bflo(u.x); acc.y += bfhi(u.x);
            acc.z += bflo(u.y); acc.w += bfhi(u.y);
        }
        *(float4*)(H + (size_t)node * HID + j0) = acc;
    }
}

// ---------------------------------------------------------------------------
// Gather-reduce (readout): O[node] = bf + sum over edges(dst==node) of S[src].
// ---------------------------------------------------------------------------
__global__ __launch_bounds__(256) void gather_scalar(
    const float* __restrict__ S, const int* __restrict__ offs,
    const int* __restrict__ srcSorted, const float* __restrict__ bf,
    float* __restrict__ O, int n_nodes)
{
    const int t  = blockIdx.x * blockDim.x + threadIdx.x;
    const int nt = gridDim.x * blockDim.x;
    for (int node = t; node < n_nodes; node += nt) {
        const int k0 = offs[node];
        const int k1 = offs[node + 1];
        float acc = bf[0];
        for (int k = k0; k < k1; ++k) acc += S[srcSorted[k]];
        O[node] = acc;
    }
}

// ---------------------------------------------------------------------------
// Fallback atomic path (used only if workspace is too small for CSR)
// ---------------------------------------------------------------------------
__global__ __launch_bounds__(256) void scatter_vec(
    const ushort_t* __restrict__ T, const int* __restrict__ E,
    const int* __restrict__ flag, float* __restrict__ H,
    int n_edges, int n_nodes)
{
    const bool is64 = (flag[0] != 0);
    const int l32 = threadIdx.x & 31;
    const int j0  = l32 * 4;
    const int grp  = (int)((blockIdx.x * blockDim.x + threadIdx.x) >> 5);
    const int ngrp = (int)((gridDim.x * blockDim.x) >> 5);
    for (int e = grp; e < n_edges; e += ngrp) {
        const int src = load_idx(E, e, is64);
        const int dst = load_idx(E, n_edges + e, is64);
        if ((unsigned)src >= (unsigned)n_nodes || (unsigned)dst >= (unsigned)n_nodes) continue;
        const uint2 u = *(const uint2*)(T + (size_t)src * HID + j0);
        float* hp = H + (size_t)dst * HID + j0;
        unsafeAtomicAdd(hp + 0, bflo(u.x));
        unsafeAtomicAdd(hp + 1, bfhi(u.x));
        unsafeAtomicAdd(hp + 2, bflo(u.y));
        unsafeAtomicAdd(hp + 3, bfhi(u.y));
    }
}

__global__ __launch_bounds__(256) void scatter_scalar(
    const float* __restrict__ S, const int* __restrict__ E,
    const int* __restrict__ flag, float* __restrict__ O,
    int n_edges, int n_nodes)
{
    const bool is64 = (flag[0] != 0);
    const int t  = blockIdx.x * blockDim.x + threadIdx.x;
    const int nt = gridDim.x * blockDim.x;
    for (int e = t; e < n_edges; e += nt) {
        const int src = load_idx(E, e, is64);
        const int dst = load_idx(E, n_edges + e, is64);
        if ((unsigned)src >= (unsigned)n_nodes || (unsigned)dst >= (unsigned)n_nodes) continue;
        unsafeAtomicAdd(O + dst, S[src]);
    }
}

__global__ void init_out(float* __restrict__ O, const float* __restrict__ bf, int n) {
    int i = blockIdx.x * blockDim.x + threadIdx.x;
    if (i < n) O[i] = bf[0];
}

extern "C" void kernel_launch(void* const* d_in, const int* in_sizes, int n_in,
                              void* d_out, int out_size, void* d_ws, size_t ws_size,
                              hipStream_t stream) {
    const float* x  = (const float*)d_in[0];
    const int*   E  = (const int*)d_in[1];
    const float* W1 = (const float*)d_in[2];
    const float* b1 = (const float*)d_in[3];
    const float* W2 = (const float*)d_in[4];
    const float* b2 = (const float*)d_in[5];
    const float* Wf = (const float*)d_in[6];
    const float* bf = (const float*)d_in[7];
    float* out = (float*)d_out;

    const int n  = in_sizes[0] / HID;   // 50000 nodes
    const int ne = in_sizes[1] / 2;     // 800000 edges
    const int nb = (n + 255) / 256;     // scan blocks

    const size_t featB = (size_t)n * HID * 4;
    char* ws = (char*)d_ws;
    int*   flag = (int*)ws;
    ushort_t* t1 = (ushort_t*)(ws + 1024);             // n*128 bf16 (within featB slot)
    float* h1   = (float*)(ws + 1024 + featB);
    char*  p    = ws + 1024 + 2 * featB;
    int*   cnt       = (int*)p;                 p += (size_t)n * 4;
    int*   offs      = (int*)p;                 p += (size_t)(n + 1) * 4;
    int*   pos       = (int*)p;                 p += (size_t)n * 4;
    int*   srcSorted = (int*)p;                 p += (size_t)ne * 4;
    int*   blockSum  = (int*)p;                 p += (size_t)nb * 4;
    const size_t needed = (size_t)(p - ws);
    float* s = (float*)(ws + 1024);   // t1 dead after aggregation; reuse slot

    const int gemm_grid = (n + BM - 1) / BM;

    detect_idx64<<<1, 64, 0, stream>>>(E, flag);

    // layer 1 per-node transform (bf16 out)
    mlp_gemm<<<gemm_grid, 256, 0, stream>>>(x, W1, b1, nullptr, t1, nullptr, n, 0);

    if (ws_size >= needed) {
        // ---- CSR build ----
        (void)hipMemsetAsync(cnt, 0, (size_t)n * 4, stream);
        hist_dst<<<1024, 256, 0, stream>>>(E, flag, cnt, ne, n);
        scan_blk<<<nb, 256, 0, stream>>>(cnt, offs, blockSum, n);
        scan_top<<<1, 256, 0, stream>>>(blockSum, offs, nb, n);
        scan_add<<<nb, 256, 0, stream>>>(offs, pos, blockSum, n);
        build_perm<<<2048, 256, 0, stream>>>(E, flag, pos, srcSorted, ne, n);

        // ---- aggregation without atomics ----
        gather_vec<<<2048, 256, 0, stream>>>(t1, offs, srcSorted, h1, n);

        // layer 2 fused with readout: s[m] = relu(h1[m]@W2+b2) . Wf
        mlp_gemm<<<gemm_grid, 256, 0, stream>>>(h1, W2, b2, Wf, nullptr, s, n, 1);

        gather_scalar<<<1024, 256, 0, stream>>>(s, offs, srcSorted, bf, out, n);
    } else {
        // ---- fallback: atomic scatter path ----
        (void)hipMemsetAsync(h1, 0, featB, stream);
        scatter_vec<<<8192, 256, 0, stream>>>(t1, E, flag, h1, ne, n);
        mlp_gemm<<<gemm_grid, 256, 0, stream>>>(h1, W2, b2, Wf, nullptr, s, n, 1);
        init_out<<<(n + 255) / 256, 256, 0, stream>>>(out, bf, n);
        scatter_scalar<<<2048, 256, 0, stream>>>(s, E, flag, out, ne, n);
    }
}

// Round 7
// 231.476 us; speedup vs baseline: 1.0859x; 1.0859x over previous
//
#include <hip/hip_runtime.h>

#define HID 128
#define BM 128
#define BK 32
#define NBLK 32          // partition chunks (blocks in part_hist/part_scatter)
#define MAXBUCK 2048     // buckets of 32 dst nodes; supports n <= 65536

typedef unsigned short ushort_t;
typedef unsigned int uint_t;

__device__ __forceinline__ float bflo(uint_t u) { return __uint_as_float(u << 16); }
__device__ __forceinline__ float bfhi(uint_t u) { return __uint_as_float(u & 0xFFFF0000u); }
__device__ __forceinline__ uint_t f2bf(float f) {
    uint_t x = __float_as_uint(f);
    return (x + 0x7FFFu + ((x >> 16) & 1u)) >> 16;   // RNE
}

// ---------------------------------------------------------------------------
// Detect whether edge_index was materialized as int64 (odd 32-bit words all 0)
// or int32. Values are node ids in [0, 50000) so the high word of int64 is 0.
// ---------------------------------------------------------------------------
__global__ void detect_idx64(const int* __restrict__ E, int* __restrict__ flag) {
    int l = threadIdx.x;                       // 64 threads
    int v = E[2 * l + 1] | E[2 * (l + 64) + 1];
    unsigned long long b = __ballot(v != 0);
    if (l == 0) flag[0] = (b == 0ull) ? 1 : 0;
}

__device__ __forceinline__ int load_idx(const int* __restrict__ E, int pos, bool is64) {
    return is64 ? E[2 * pos] : E[pos];
}

// ---------------------------------------------------------------------------
// Register-blocked SGEMM: T = relu(X @ W + B)  (X: n x 128, W: 128 x 128)
// Block: 256 threads (16x16), tile BM=128 rows, BK=32 k-slice, 8x8 micro-tile.
// mode 0: write full T rows as bf16.  mode 1: fuse dot with Wf, write S only.
// ---------------------------------------------------------------------------
__global__ __launch_bounds__(256, 2) void mlp_gemm(
    const float* __restrict__ X, const float* __restrict__ W,
    const float* __restrict__ Bv, const float* __restrict__ Wf,
    ushort_t* __restrict__ T, float* __restrict__ S, int n, int mode)
{
    __shared__ float Xs[BK][BM + 1];     // transposed X tile, +1 pad
    __shared__ float Wsh[BK][HID];       // W k-slice, natural layout

    const int t  = threadIdx.x;
    const int tn = t & 15;               // column-group 0..15 (8 cols each)
    const int tm = t >> 4;               // row-group 0..15 (8 rows each)
    const int base = blockIdx.x * BM;

    float acc[8][8];
#pragma unroll
    for (int r = 0; r < 8; ++r)
#pragma unroll
        for (int c = 0; c < 8; ++c) acc[r][c] = 0.f;

    for (int kb = 0; kb < HID; kb += BK) {
#pragma unroll
        for (int pass = 0; pass < 4; ++pass) {
            const int row = pass * 32 + (t >> 3);
            const int kc  = (t & 7) * 4;
            float4 v = {0.f, 0.f, 0.f, 0.f};
            const int gr = base + row;
            if (gr < n) v = *(const float4*)(X + (size_t)gr * HID + kb + kc);
            Xs[kc + 0][row] = v.x;
            Xs[kc + 1][row] = v.y;
            Xs[kc + 2][row] = v.z;
            Xs[kc + 3][row] = v.w;
        }
#pragma unroll
        for (int pass = 0; pass < 4; ++pass) {
            const int kr = pass * 8 + (t >> 5);
            const int nc = (t & 31) * 4;
            *(float4*)(&Wsh[kr][nc]) =
                *(const float4*)(W + (size_t)(kb + kr) * HID + nc);
        }
        __syncthreads();

#pragma unroll
        for (int k = 0; k < BK; ++k) {
            float xr[8], wc[8];
            *(float4*)&xr[0] = *(const float4*)&Xs[k][tm * 8];
            *(float4*)&xr[4] = *(const float4*)&Xs[k][tm * 8 + 4];
            *(float4*)&wc[0] = *(const float4*)&Wsh[k][tn * 8];
            *(float4*)&wc[4] = *(const float4*)&Wsh[k][tn * 8 + 4];
#pragma unroll
            for (int r = 0; r < 8; ++r)
#pragma unroll
                for (int c = 0; c < 8; ++c)
                    acc[r][c] = fmaf(xr[r], wc[c], acc[r][c]);
        }
        __syncthreads();
    }

    float bv[8];
    *(float4*)&bv[0] = *(const float4*)(Bv + tn * 8);
    *(float4*)&bv[4] = *(const float4*)(Bv + tn * 8 + 4);

    if (mode == 0) {
#pragma unroll
        for (int r = 0; r < 8; ++r) {
            const int gr = base + tm * 8 + r;
            if (gr >= n) break;
            uint_t w[4];
#pragma unroll
            for (int c = 0; c < 4; ++c) {
                const float lo = fmaxf(acc[r][2 * c]     + bv[2 * c],     0.f);
                const float hi = fmaxf(acc[r][2 * c + 1] + bv[2 * c + 1], 0.f);
                w[c] = f2bf(lo) | (f2bf(hi) << 16);
            }
            *(uint4*)(T + (size_t)gr * HID + tn * 8) = *(uint4*)&w[0];
        }
    } else {
        float wf[8];
        *(float4*)&wf[0] = *(const float4*)(Wf + tn * 8);
        *(float4*)&wf[4] = *(const float4*)(Wf + tn * 8 + 4);
        float p[8];
#pragma unroll
        for (int r = 0; r < 8; ++r) {
            float s = 0.f;
#pragma unroll
            for (int c = 0; c < 8; ++c)
                s += fmaxf(acc[r][c] + bv[c], 0.f) * wf[c];
            p[r] = s;
        }
#pragma unroll
        for (int m = 1; m <= 8; m <<= 1)
#pragma unroll
            for (int r = 0; r < 8; ++r) p[r] += __shfl_xor(p[r], m);
        if (tn == 0) {
#pragma unroll
            for (int r = 0; r < 8; ++r) {
                const int gr = base + tm * 8 + r;
                if (gr < n) S[gr] = p[r];
            }
        }
    }
}

// ---------------------------------------------------------------------------
// Partition stage 1: per-block LDS histogram of dst buckets (32 dsts/bucket).
// No global atomics. histT layout: [bucket][blk] for linear scan.
// ---------------------------------------------------------------------------
__global__ __launch_bounds__(256) void part_hist(
    const int* __restrict__ E, const int* __restrict__ flag,
    int* __restrict__ histT, int n_edges, int n_nodes, int nbuck)
{
    __shared__ int h[MAXBUCK];
    for (int i = threadIdx.x; i < nbuck; i += 256) h[i] = 0;
    __syncthreads();
    const bool is64 = (flag[0] != 0);
    const int chunk = (n_edges + NBLK - 1) / NBLK;
    const int c0 = blockIdx.x * chunk;
    const int c1 = min(c0 + chunk, n_edges);
    for (int e = c0 + threadIdx.x; e < c1; e += 256) {
        const int dst = load_idx(E, n_edges + e, is64);
        if ((unsigned)dst < (unsigned)n_nodes) atomicAdd(&h[dst >> 5], 1);
    }
    __syncthreads();
    for (int i = threadIdx.x; i < nbuck; i += 256)
        histT[i * NBLK + blockIdx.x] = h[i];
}

// ---------------------------------------------------------------------------
// Generic hierarchical exclusive scan (3 kernels) over m elements.
// ---------------------------------------------------------------------------
__global__ __launch_bounds__(256) void scang_blk(
    const int* __restrict__ A, int* __restrict__ out,
    int* __restrict__ bsum, int m)
{
    __shared__ int sd[256];
    const int t = threadIdx.x;
    const int i = blockIdx.x * 256 + t;
    const int v = (i < m) ? A[i] : 0;
    sd[t] = v;
    __syncthreads();
    for (int d = 1; d < 256; d <<= 1) {
        const int u = (t >= d) ? sd[t - d] : 0;
        __syncthreads();
        sd[t] += u;
        __syncthreads();
    }
    if (i < m) out[i] = sd[t] - v;           // local exclusive
    if (t == 255) bsum[blockIdx.x] = sd[255];
}

__global__ __launch_bounds__(256) void scang_top(
    int* __restrict__ bsum, int* __restrict__ totalSlot, int nb)
{
    __shared__ int sd[256];
    const int t = threadIdx.x;
    const int chunk = (nb + 255) / 256;
    const int lo = t * chunk;
    const int hi = min(lo + chunk, nb);
    int s = 0;
    for (int i = lo; i < hi; ++i) s += bsum[i];
    sd[t] = s;
    __syncthreads();
    for (int d = 1; d < 256; d <<= 1) {
        const int u = (t >= d) ? sd[t - d] : 0;
        __syncthreads();
        sd[t] += u;
        __syncthreads();
    }
    int run = sd[t] - s;
    for (int i = lo; i < hi; ++i) {
        const int c = bsum[i];
        bsum[i] = run;                        // block base
        run += c;
    }
    if (t == 255) totalSlot[0] = sd[255];
}

__global__ __launch_bounds__(256) void scang_add(
    int* __restrict__ out, const int* __restrict__ bsum, int m)
{
    const int i = blockIdx.x * 256 + threadIdx.x;
    if (i < m) out[i] += bsum[blockIdx.x];
}

// ---------------------------------------------------------------------------
// Partition stage 2: scatter packed (src | dlow<<16) into per-(block,bucket)
// EXCLUSIVE ranges. Positions from LDS counters -> no global atomics; each
// output line is written by exactly one block -> L2 write-combining works.
// ---------------------------------------------------------------------------
__global__ __launch_bounds__(256) void part_scatter(
    const int* __restrict__ E, const int* __restrict__ flag,
    const int* __restrict__ base, uint_t* __restrict__ pe,
    int n_edges, int n_nodes, int nbuck)
{
    __shared__ int cur[MAXBUCK];
    for (int i = threadIdx.x; i < nbuck; i += 256)
        cur[i] = base[i * NBLK + blockIdx.x];
    __syncthreads();
    const bool is64 = (flag[0] != 0);
    const int chunk = (n_edges + NBLK - 1) / NBLK;
    const int c0 = blockIdx.x * chunk;
    const int c1 = min(c0 + chunk, n_edges);
    for (int e = c0 + threadIdx.x; e < c1; e += 256) {
        const int src = load_idx(E, e, is64);
        const int dst = load_idx(E, n_edges + e, is64);
        if ((unsigned)src >= (unsigned)n_nodes || (unsigned)dst >= (unsigned)n_nodes) continue;
        const int p = atomicAdd(&cur[dst >> 5], 1);
        pe[p] = (uint_t)src | ((uint_t)(dst & 31) << 16);
    }
}

// ---------------------------------------------------------------------------
// Per-bucket exact CSR: one wave per bucket of 32 dsts. Count per dst,
// shfl-scan, write offs[dst] and place src into block-exclusive region.
// ---------------------------------------------------------------------------
__global__ __launch_bounds__(64) void bucket_csr(
    const uint_t* __restrict__ pe, const int* __restrict__ base,
    int* __restrict__ offs, int* __restrict__ srcS,
    int n_nodes, int nbuck)
{
    __shared__ int cnt[32];
    __shared__ int cur[32];
    const int b = blockIdx.x;
    const int l = threadIdx.x;
    const int start = base[b * NBLK];
    const int end   = base[(b + 1) * NBLK];   // base has nbuck*NBLK+1 entries
    if (l < 32) cnt[l] = 0;
    __syncthreads();
    for (int i = start + l; i < end; i += 64)
        atomicAdd(&cnt[(pe[i] >> 16) & 31], 1);
    __syncthreads();
    if (l < 32) {
        const int v = cnt[l];
        int s = v;
        for (int d = 1; d < 32; d <<= 1) {
            const int u = __shfl_up(s, d, 64);
            if (l >= d) s += u;
        }
        const int o = start + s - v;          // exclusive within bucket
        const int dst = b * 32 + l;
        if (dst < n_nodes) offs[dst] = o;
        cur[l] = o;
    }
    __syncthreads();
    for (int i = start + l; i < end; i += 64) {
        const uint_t w = pe[i];
        const int p = atomicAdd(&cur[(w >> 16) & 31], 1);
        srcS[p] = (int)(w & 0xFFFFu);
    }
    if (b == 0 && l == 0) offs[n_nodes] = base[nbuck * NBLK];
}

// ---------------------------------------------------------------------------
// Gather-reduce (layer 1): H[node] = sum over edges(dst==node) of T[src].
// One 32-lane group per node, lane owns 4 features (bf16 in T, fp32 acc).
// ---------------------------------------------------------------------------
__global__ __launch_bounds__(256) void gather_vec(
    const ushort_t* __restrict__ T, const int* __restrict__ offs,
    const int* __restrict__ srcSorted, float* __restrict__ H, int n_nodes)
{
    const int l32  = threadIdx.x & 31;
    const int j0   = l32 * 4;
    const int grp  = (int)((blockIdx.x * blockDim.x + threadIdx.x) >> 5);
    const int ngrp = (int)((gridDim.x * blockDim.x) >> 5);
    for (int node = grp; node < n_nodes; node += ngrp) {
        const int k0 = offs[node];
        const int k1 = offs[node + 1];
        float4 acc = {0.f, 0.f, 0.f, 0.f};
        for (int k = k0; k < k1; ++k) {
            const int s = srcSorted[k];
            const uint2 u = *(const uint2*)(T + (size_t)s * HID + j0);
            acc.x += bflo(u.x); acc.y += bfhi(u.x);
            acc.z += bflo(u.y); acc.w += bfhi(u.y);
        }
        *(float4*)(H + (size_t)node * HID + j0) = acc;
    }
}

// ---------------------------------------------------------------------------
// Gather-reduce (readout): O[node] = bf + sum over edges(dst==node) of S[src].
// ---------------------------------------------------------------------------
__global__ __launch_bounds__(256) void gather_scalar(
    const float* __restrict__ S, const int* __restrict__ offs,
    const int* __restrict__ srcSorted, const float* __restrict__ bf,
    float* __restrict__ O, int n_nodes)
{
    const int t  = blockIdx.x * blockDim.x + threadIdx.x;
    const int nt = gridDim.x * blockDim.x;
    for (int node = t; node < n_nodes; node += nt) {
        const int k0 = offs[node];
        const int k1 = offs[node + 1];
        float acc = bf[0];
        for (int k = k0; k < k1; ++k) acc += S[srcSorted[k]];
        O[node] = acc;
    }
}

// ---------------------------------------------------------------------------
// Fallback atomic path (used only if workspace is too small for CSR)
// ---------------------------------------------------------------------------
__global__ __launch_bounds__(256) void scatter_vec(
    const ushort_t* __restrict__ T, const int* __restrict__ E,
    const int* __restrict__ flag, float* __restrict__ H,
    int n_edges, int n_nodes)
{
    const bool is64 = (flag[0] != 0);
    const int l32 = threadIdx.x & 31;
    const int j0  = l32 * 4;
    const int grp  = (int)((blockIdx.x * blockDim.x + threadIdx.x) >> 5);
    const int ngrp = (int)((gridDim.x * blockDim.x) >> 5);
    for (int e = grp; e < n_edges; e += ngrp) {
        const int src = load_idx(E, e, is64);
        const int dst = load_idx(E, n_edges + e, is64);
        if ((unsigned)src >= (unsigned)n_nodes || (unsigned)dst >= (unsigned)n_nodes) continue;
        const uint2 u = *(const uint2*)(T + (size_t)src * HID + j0);
        float* hp = H + (size_t)dst * HID + j0;
        unsafeAtomicAdd(hp + 0, bflo(u.x));
        unsafeAtomicAdd(hp + 1, bfhi(u.x));
        unsafeAtomicAdd(hp + 2, bflo(u.y));
        unsafeAtomicAdd(hp + 3, bfhi(u.y));
    }
}

__global__ __launch_bounds__(256) void scatter_scalar(
    const float* __restrict__ S, const int* __restrict__ E,
    const int* __restrict__ flag, float* __restrict__ O,
    int n_edges, int n_nodes)
{
    const bool is64 = (flag[0] != 0);
    const int t  = blockIdx.x * blockDim.x + threadIdx.x;
    const int nt = gridDim.x * blockDim.x;
    for (int e = t; e < n_edges; e += nt) {
        const int src = load_idx(E, e, is64);
        const int dst = load_idx(E, n_edges + e, is64);
        if ((unsigned)src >= (unsigned)n_nodes || (unsigned)dst >= (unsigned)n_nodes) continue;
        unsafeAtomicAdd(O + dst, S[src]);
    }
}

__global__ void init_out(float* __restrict__ O, const float* __restrict__ bf, int n) {
    int i = blockIdx.x * blockDim.x + threadIdx.x;
    if (i < n) O[i] = bf[0];
}

extern "C" void kernel_launch(void* const* d_in, const int* in_sizes, int n_in,
                              void* d_out, int out_size, void* d_ws, size_t ws_size,
                              hipStream_t stream) {
    const float* x  = (const float*)d_in[0];
    const int*   E  = (const int*)d_in[1];
    const float* W1 = (const float*)d_in[2];
    const float* b1 = (const float*)d_in[3];
    const float* W2 = (const float*)d_in[4];
    const float* b2 = (const float*)d_in[5];
    const float* Wf = (const float*)d_in[6];
    const float* bf = (const float*)d_in[7];
    float* out = (float*)d_out;

    const int n  = in_sizes[0] / HID;   // 50000 nodes
    const int ne = in_sizes[1] / 2;     // 800000 edges
    const int nbuck  = (n + 31) / 32;   // 1563 buckets
    const int m      = nbuck * NBLK;    // 50016 partition counters
    const int nbscan = (m + 255) / 256; // 196 scan blocks

    const size_t featB = (size_t)n * HID * 4;
    char* ws = (char*)d_ws;
    int*   flag = (int*)ws;
    ushort_t* t1 = (ushort_t*)(ws + 1024);             // n*128 bf16 (in featB slot)
    float* h1   = (float*)(ws + 1024 + featB);
    char*  p    = ws + 1024 + 2 * featB;
    uint_t* pe       = (uint_t*)p;              p += (size_t)ne * 4;
    int*   srcSorted = (int*)p;                 p += (size_t)ne * 4;
    int*   offs      = (int*)p;                 p += (size_t)(n + 1) * 4;
    int*   histT     = (int*)p;                 p += (size_t)m * 4;
    int*   basea     = (int*)p;                 p += (size_t)(m + 1) * 4;
    int*   bsum      = (int*)p;                 p += (size_t)nbscan * 4;
    const size_t needed = (size_t)(p - ws);
    float* s = (float*)(ws + 1024);   // t1 dead after aggregation; reuse slot

    const int gemm_grid = (n + BM - 1) / BM;

    detect_idx64<<<1, 64, 0, stream>>>(E, flag);

    // layer 1 per-node transform (bf16 out)
    mlp_gemm<<<gemm_grid, 256, 0, stream>>>(x, W1, b1, nullptr, t1, nullptr, n, 0);

    if (ws_size >= needed && n <= 65536 && nbuck <= MAXBUCK) {
        // ---- coalesced counting partition + exact per-bucket CSR ----
        part_hist<<<NBLK, 256, 0, stream>>>(E, flag, histT, ne, n, nbuck);
        scang_blk<<<nbscan, 256, 0, stream>>>(histT, basea, bsum, m);
        scang_top<<<1, 256, 0, stream>>>(bsum, basea + m, nbscan);
        scang_add<<<nbscan, 256, 0, stream>>>(basea, bsum, m);
        part_scatter<<<NBLK, 256, 0, stream>>>(E, flag, basea, pe, ne, n, nbuck);
        bucket_csr<<<nbuck, 64, 0, stream>>>(pe, basea, offs, srcSorted, n, nbuck);

        // ---- aggregation without atomics ----
        gather_vec<<<2048, 256, 0, stream>>>(t1, offs, srcSorted, h1, n);

        // layer 2 fused with readout: s[m] = relu(h1[m]@W2+b2) . Wf
        mlp_gemm<<<gemm_grid, 256, 0, stream>>>(h1, W2, b2, Wf, nullptr, s, n, 1);

        gather_scalar<<<1024, 256, 0, stream>>>(s, offs, srcSorted, bf, out, n);
    } else {
        // ---- fallback: atomic scatter path ----
        (void)hipMemsetAsync(h1, 0, featB, stream);
        scatter_vec<<<8192, 256, 0, stream>>>(t1, E, flag, h1, ne, n);
        mlp_gemm<<<gemm_grid, 256, 0, stream>>>(h1, W2, b2, Wf, nullptr, s, n, 1);
        init_out<<<(n + 255) / 256, 256, 0, stream>>>(out, bf, n);
        scatter_scalar<<<2048, 256, 0, stream>>>(s, E, flag, out, ne, n);
    }
}

// Round 8
// 162.938 us; speedup vs baseline: 1.5426x; 1.4206x over previous
//
#include <hip/hip_runtime.h>

#define HID 128
#define BM 128
#define BK 32
#define NBLK 64          // partition chunks (blocks in part_hist/part_scatter)
#define PTHREADS 1024    // threads per partition block
#define MAXBUCK 2048     // buckets of 32 dst nodes; supports n <= 65536

typedef unsigned short ushort_t;
typedef unsigned int uint_t;

__device__ __forceinline__ float bflo(uint_t u) { return __uint_as_float(u << 16); }
__device__ __forceinline__ float bfhi(uint_t u) { return __uint_as_float(u & 0xFFFF0000u); }
__device__ __forceinline__ uint_t f2bf(float f) {
    uint_t x = __float_as_uint(f);
    return (x + 0x7FFFu + ((x >> 16) & 1u)) >> 16;   // RNE
}

// ---------------------------------------------------------------------------
// Detect whether edge_index was materialized as int64 (odd 32-bit words all 0)
// or int32. Values are node ids in [0, 50000) so the high word of int64 is 0.
// ---------------------------------------------------------------------------
__global__ void detect_idx64(const int* __restrict__ E, int* __restrict__ flag) {
    int l = threadIdx.x;                       // 64 threads
    int v = E[2 * l + 1] | E[2 * (l + 64) + 1];
    unsigned long long b = __ballot(v != 0);
    if (l == 0) flag[0] = (b == 0ull) ? 1 : 0;
}

__device__ __forceinline__ int load_idx(const int* __restrict__ E, int pos, bool is64) {
    return is64 ? E[2 * pos] : E[pos];
}

// ---------------------------------------------------------------------------
// Register-blocked SGEMM: T = relu(X @ W + B)  (X: n x 128, W: 128 x 128)
// Block: 256 threads (16x16), tile BM=128 rows, BK=32 k-slice, 8x8 micro-tile.
// mode 0: write full T rows as bf16.  mode 1: fuse dot with Wf, write S only.
// ---------------------------------------------------------------------------
__global__ __launch_bounds__(256, 2) void mlp_gemm(
    const float* __restrict__ X, const float* __restrict__ W,
    const float* __restrict__ Bv, const float* __restrict__ Wf,
    ushort_t* __restrict__ T, float* __restrict__ S, int n, int mode)
{
    __shared__ float Xs[BK][BM + 1];     // transposed X tile, +1 pad
    __shared__ float Wsh[BK][HID];       // W k-slice, natural layout

    const int t  = threadIdx.x;
    const int tn = t & 15;               // column-group 0..15 (8 cols each)
    const int tm = t >> 4;               // row-group 0..15 (8 rows each)
    const int base = blockIdx.x * BM;

    float acc[8][8];
#pragma unroll
    for (int r = 0; r < 8; ++r)
#pragma unroll
        for (int c = 0; c < 8; ++c) acc[r][c] = 0.f;

    for (int kb = 0; kb < HID; kb += BK) {
#pragma unroll
        for (int pass = 0; pass < 4; ++pass) {
            const int row = pass * 32 + (t >> 3);
            const int kc  = (t & 7) * 4;
            float4 v = {0.f, 0.f, 0.f, 0.f};
            const int gr = base + row;
            if (gr < n) v = *(const float4*)(X + (size_t)gr * HID + kb + kc);
            Xs[kc + 0][row] = v.x;
            Xs[kc + 1][row] = v.y;
            Xs[kc + 2][row] = v.z;
            Xs[kc + 3][row] = v.w;
        }
#pragma unroll
        for (int pass = 0; pass < 4; ++pass) {
            const int kr = pass * 8 + (t >> 5);
            const int nc = (t & 31) * 4;
            *(float4*)(&Wsh[kr][nc]) =
                *(const float4*)(W + (size_t)(kb + kr) * HID + nc);
        }
        __syncthreads();

#pragma unroll
        for (int k = 0; k < BK; ++k) {
            float xr[8], wc[8];
            *(float4*)&xr[0] = *(const float4*)&Xs[k][tm * 8];
            *(float4*)&xr[4] = *(const float4*)&Xs[k][tm * 8 + 4];
            *(float4*)&wc[0] = *(const float4*)&Wsh[k][tn * 8];
            *(float4*)&wc[4] = *(const float4*)&Wsh[k][tn * 8 + 4];
#pragma unroll
            for (int r = 0; r < 8; ++r)
#pragma unroll
                for (int c = 0; c < 8; ++c)
                    acc[r][c] = fmaf(xr[r], wc[c], acc[r][c]);
        }
        __syncthreads();
    }

    float bv[8];
    *(float4*)&bv[0] = *(const float4*)(Bv + tn * 8);
    *(float4*)&bv[4] = *(const float4*)(Bv + tn * 8 + 4);

    if (mode == 0) {
#pragma unroll
        for (int r = 0; r < 8; ++r) {
            const int gr = base + tm * 8 + r;
            if (gr >= n) break;
            uint_t w[4];
#pragma unroll
            for (int c = 0; c < 4; ++c) {
                const float lo = fmaxf(acc[r][2 * c]     + bv[2 * c],     0.f);
                const float hi = fmaxf(acc[r][2 * c + 1] + bv[2 * c + 1], 0.f);
                w[c] = f2bf(lo) | (f2bf(hi) << 16);
            }
            *(uint4*)(T + (size_t)gr * HID + tn * 8) = *(uint4*)&w[0];
        }
    } else {
        float wf[8];
        *(float4*)&wf[0] = *(const float4*)(Wf + tn * 8);
        *(float4*)&wf[4] = *(const float4*)(Wf + tn * 8 + 4);
        float p[8];
#pragma unroll
        for (int r = 0; r < 8; ++r) {
            float s = 0.f;
#pragma unroll
            for (int c = 0; c < 8; ++c)
                s += fmaxf(acc[r][c] + bv[c], 0.f) * wf[c];
            p[r] = s;
        }
#pragma unroll
        for (int m = 1; m <= 8; m <<= 1)
#pragma unroll
            for (int r = 0; r < 8; ++r) p[r] += __shfl_xor(p[r], m);
        if (tn == 0) {
#pragma unroll
            for (int r = 0; r < 8; ++r) {
                const int gr = base + tm * 8 + r;
                if (gr < n) S[gr] = p[r];
            }
        }
    }
}

// ---------------------------------------------------------------------------
// Partition stage 1: per-block LDS histogram of dst buckets (32 dsts/bucket).
// No global atomics. histT layout: [bucket][blk] for linear scan.
// ---------------------------------------------------------------------------
__global__ __launch_bounds__(PTHREADS) void part_hist(
    const int* __restrict__ E, const int* __restrict__ flag,
    int* __restrict__ histT, int n_edges, int n_nodes, int nbuck)
{
    __shared__ int h[MAXBUCK];
    for (int i = threadIdx.x; i < nbuck; i += PTHREADS) h[i] = 0;
    __syncthreads();
    const bool is64 = (flag[0] != 0);
    const int chunk = (n_edges + NBLK - 1) / NBLK;
    const int c0 = blockIdx.x * chunk;
    const int c1 = min(c0 + chunk, n_edges);
    for (int e = c0 + (int)threadIdx.x; e < c1; e += PTHREADS) {
        const int dst = load_idx(E, n_edges + e, is64);
        if ((unsigned)dst < (unsigned)n_nodes) atomicAdd(&h[dst >> 5], 1);
    }
    __syncthreads();
    for (int i = threadIdx.x; i < nbuck; i += PTHREADS)
        histT[i * NBLK + blockIdx.x] = h[i];
}

// ---------------------------------------------------------------------------
// Generic hierarchical exclusive scan (3 kernels) over m elements.
// ---------------------------------------------------------------------------
__global__ __launch_bounds__(256) void scang_blk(
    const int* __restrict__ A, int* __restrict__ out,
    int* __restrict__ bsum, int m)
{
    __shared__ int sd[256];
    const int t = threadIdx.x;
    const int i = blockIdx.x * 256 + t;
    const int v = (i < m) ? A[i] : 0;
    sd[t] = v;
    __syncthreads();
    for (int d = 1; d < 256; d <<= 1) {
        const int u = (t >= d) ? sd[t - d] : 0;
        __syncthreads();
        sd[t] += u;
        __syncthreads();
    }
    if (i < m) out[i] = sd[t] - v;           // local exclusive
    if (t == 255) bsum[blockIdx.x] = sd[255];
}

__global__ __launch_bounds__(256) void scang_top(
    int* __restrict__ bsum, int* __restrict__ totalSlot, int nb)
{
    __shared__ int sd[256];
    const int t = threadIdx.x;
    const int chunk = (nb + 255) / 256;
    const int lo = t * chunk;
    const int hi = min(lo + chunk, nb);
    int s = 0;
    for (int i = lo; i < hi; ++i) s += bsum[i];
    sd[t] = s;
    __syncthreads();
    for (int d = 1; d < 256; d <<= 1) {
        const int u = (t >= d) ? sd[t - d] : 0;
        __syncthreads();
        sd[t] += u;
        __syncthreads();
    }
    int run = sd[t] - s;
    for (int i = lo; i < hi; ++i) {
        const int c = bsum[i];
        bsum[i] = run;                        // block base
        run += c;
    }
    if (t == 255) totalSlot[0] = sd[255];
}

__global__ __launch_bounds__(256) void scang_add(
    int* __restrict__ out, const int* __restrict__ bsum, int m)
{
    const int i = blockIdx.x * 256 + threadIdx.x;
    if (i < m) out[i] += bsum[blockIdx.x];
}

// ---------------------------------------------------------------------------
// Partition stage 2: scatter packed (src | dlow<<16) into per-(block,bucket)
// EXCLUSIVE ranges. Positions from LDS counters -> no global atomics; each
// output region is written by exactly one block -> L2 write-combining works.
// ---------------------------------------------------------------------------
__global__ __launch_bounds__(PTHREADS) void part_scatter(
    const int* __restrict__ E, const int* __restrict__ flag,
    const int* __restrict__ base, uint_t* __restrict__ pe,
    int n_edges, int n_nodes, int nbuck)
{
    __shared__ int cur[MAXBUCK];
    for (int i = threadIdx.x; i < nbuck; i += PTHREADS)
        cur[i] = base[i * NBLK + blockIdx.x];
    __syncthreads();
    const bool is64 = (flag[0] != 0);
    const int chunk = (n_edges + NBLK - 1) / NBLK;
    const int c0 = blockIdx.x * chunk;
    const int c1 = min(c0 + chunk, n_edges);
    for (int e = c0 + (int)threadIdx.x; e < c1; e += PTHREADS) {
        const int src = load_idx(E, e, is64);
        const int dst = load_idx(E, n_edges + e, is64);
        if ((unsigned)src >= (unsigned)n_nodes || (unsigned)dst >= (unsigned)n_nodes) continue;
        const int p = atomicAdd(&cur[dst >> 5], 1);
        pe[p] = (uint_t)src | ((uint_t)(dst & 31) << 16);
    }
}

// ---------------------------------------------------------------------------
// Per-bucket exact CSR: one wave per bucket of 32 dsts. Count per dst,
// shfl-scan, write offs[dst] and place src into block-exclusive region.
// ---------------------------------------------------------------------------
__global__ __launch_bounds__(64) void bucket_csr(
    const uint_t* __restrict__ pe, const int* __restrict__ base,
    int* __restrict__ offs, int* __restrict__ srcS,
    int n_nodes, int nbuck)
{
    __shared__ int cnt[32];
    __shared__ int cur[32];
    const int b = blockIdx.x;
    const int l = threadIdx.x;
    const int start = base[b * NBLK];
    const int end   = base[(b + 1) * NBLK];   // base has nbuck*NBLK+1 entries
    if (l < 32) cnt[l] = 0;
    __syncthreads();
    for (int i = start + l; i < end; i += 64)
        atomicAdd(&cnt[(pe[i] >> 16) & 31], 1);
    __syncthreads();
    if (l < 32) {
        const int v = cnt[l];
        int s = v;
        for (int d = 1; d < 32; d <<= 1) {
            const int u = __shfl_up(s, d, 64);
            if (l >= d) s += u;
        }
        const int o = start + s - v;          // exclusive within bucket
        const int dst = b * 32 + l;
        if (dst < n_nodes) offs[dst] = o;
        cur[l] = o;
    }
    __syncthreads();
    for (int i = start + l; i < end; i += 64) {
        const uint_t w = pe[i];
        const int p = atomicAdd(&cur[(w >> 16) & 31], 1);
        srcS[p] = (int)(w & 0xFFFFu);
    }
    if (b == 0 && l == 0) offs[n_nodes] = base[nbuck * NBLK];
}

// ---------------------------------------------------------------------------
// Gather-reduce (layer 1): H[node] = sum over edges(dst==node) of T[src].
// One 32-lane group per node, lane owns 4 features (bf16 in T, fp32 acc).
// Unrolled by 2: two independent load->add chains in flight.
// ---------------------------------------------------------------------------
__global__ __launch_bounds__(256) void gather_vec(
    const ushort_t* __restrict__ T, const int* __restrict__ offs,
    const int* __restrict__ srcSorted, float* __restrict__ H, int n_nodes)
{
    const int l32  = threadIdx.x & 31;
    const int j0   = l32 * 4;
    const int grp  = (int)((blockIdx.x * blockDim.x + threadIdx.x) >> 5);
    const int ngrp = (int)((gridDim.x * blockDim.x) >> 5);
    for (int node = grp; node < n_nodes; node += ngrp) {
        const int k0 = offs[node];
        const int k1 = offs[node + 1];
        float4 a0 = {0.f, 0.f, 0.f, 0.f};
        float4 a1 = {0.f, 0.f, 0.f, 0.f};
        int k = k0;
        for (; k + 1 < k1; k += 2) {
            const int s0 = srcSorted[k];
            const int s1 = srcSorted[k + 1];
            const uint2 u0 = *(const uint2*)(T + (size_t)s0 * HID + j0);
            const uint2 u1 = *(const uint2*)(T + (size_t)s1 * HID + j0);
            a0.x += bflo(u0.x); a0.y += bfhi(u0.x);
            a0.z += bflo(u0.y); a0.w += bfhi(u0.y);
            a1.x += bflo(u1.x); a1.y += bfhi(u1.x);
            a1.z += bflo(u1.y); a1.w += bfhi(u1.y);
        }
        if (k < k1) {
            const int s0 = srcSorted[k];
            const uint2 u0 = *(const uint2*)(T + (size_t)s0 * HID + j0);
            a0.x += bflo(u0.x); a0.y += bfhi(u0.x);
            a0.z += bflo(u0.y); a0.w += bfhi(u0.y);
        }
        a0.x += a1.x; a0.y += a1.y; a0.z += a1.z; a0.w += a1.w;
        *(float4*)(H + (size_t)node * HID + j0) = a0;
    }
}

// ---------------------------------------------------------------------------
// Gather-reduce (readout): O[node] = bf + sum over edges(dst==node) of S[src].
// ---------------------------------------------------------------------------
__global__ __launch_bounds__(256) void gather_scalar(
    const float* __restrict__ S, const int* __restrict__ offs,
    const int* __restrict__ srcSorted, const float* __restrict__ bf,
    float* __restrict__ O, int n_nodes)
{
    const int t  = blockIdx.x * blockDim.x + threadIdx.x;
    const int nt = gridDim.x * blockDim.x;
    for (int node = t; node < n_nodes; node += nt) {
        const int k0 = offs[node];
        const int k1 = offs[node + 1];
        float acc = bf[0];
        for (int k = k0; k < k1; ++k) acc += S[srcSorted[k]];
        O[node] = acc;
    }
}

// ---------------------------------------------------------------------------
// Fallback atomic path (used only if workspace is too small for CSR)
// ---------------------------------------------------------------------------
__global__ __launch_bounds__(256) void scatter_vec(
    const ushort_t* __restrict__ T, const int* __restrict__ E,
    const int* __restrict__ flag, float* __restrict__ H,
    int n_edges, int n_nodes)
{
    const bool is64 = (flag[0] != 0);
    const int l32 = threadIdx.x & 31;
    const int j0  = l32 * 4;
    const int grp  = (int)((blockIdx.x * blockDim.x + threadIdx.x) >> 5);
    const int ngrp = (int)((gridDim.x * blockDim.x) >> 5);
    for (int e = grp; e < n_edges; e += ngrp) {
        const int src = load_idx(E, e, is64);
        const int dst = load_idx(E, n_edges + e, is64);
        if ((unsigned)src >= (unsigned)n_nodes || (unsigned)dst >= (unsigned)n_nodes) continue;
        const uint2 u = *(const uint2*)(T + (size_t)src * HID + j0);
        float* hp = H + (size_t)dst * HID + j0;
        unsafeAtomicAdd(hp + 0, bflo(u.x));
        unsafeAtomicAdd(hp + 1, bfhi(u.x));
        unsafeAtomicAdd(hp + 2, bflo(u.y));
        unsafeAtomicAdd(hp + 3, bfhi(u.y));
    }
}

__global__ __launch_bounds__(256) void scatter_scalar(
    const float* __restrict__ S, const int* __restrict__ E,
    const int* __restrict__ flag, float* __restrict__ O,
    int n_edges, int n_nodes)
{
    const bool is64 = (flag[0] != 0);
    const int t  = blockIdx.x * blockDim.x + threadIdx.x;
    const int nt = gridDim.x * blockDim.x;
    for (int e = t; e < n_edges; e += nt) {
        const int src = load_idx(E, e, is64);
        const int dst = load_idx(E, n_edges + e, is64);
        if ((unsigned)src >= (unsigned)n_nodes || (unsigned)dst >= (unsigned)n_nodes) continue;
        unsafeAtomicAdd(O + dst, S[src]);
    }
}

__global__ void init_out(float* __restrict__ O, const float* __restrict__ bf, int n) {
    int i = blockIdx.x * blockDim.x + threadIdx.x;
    if (i < n) O[i] = bf[0];
}

extern "C" void kernel_launch(void* const* d_in, const int* in_sizes, int n_in,
                              void* d_out, int out_size, void* d_ws, size_t ws_size,
                              hipStream_t stream) {
    const float* x  = (const float*)d_in[0];
    const int*   E  = (const int*)d_in[1];
    const float* W1 = (const float*)d_in[2];
    const float* b1 = (const float*)d_in[3];
    const float* W2 = (const float*)d_in[4];
    const float* b2 = (const float*)d_in[5];
    const float* Wf = (const float*)d_in[6];
    const float* bf = (const float*)d_in[7];
    float* out = (float*)d_out;

    const int n  = in_sizes[0] / HID;   // 50000 nodes
    const int ne = in_sizes[1] / 2;     // 800000 edges
    const int nbuck  = (n + 31) / 32;   // 1563 buckets
    const int m      = nbuck * NBLK;    // 100k partition counters
    const int nbscan = (m + 255) / 256; // scan blocks

    const size_t featB = (size_t)n * HID * 4;
    char* ws = (char*)d_ws;
    int*   flag = (int*)ws;
    ushort_t* t1 = (ushort_t*)(ws + 1024);             // n*128 bf16 (in featB slot)
    float* h1   = (float*)(ws + 1024 + featB);
    char*  p    = ws + 1024 + 2 * featB;
    uint_t* pe       = (uint_t*)p;              p += (size_t)ne * 4;
    int*   srcSorted = (int*)p;                 p += (size_t)ne * 4;
    int*   offs      = (int*)p;                 p += (size_t)(n + 1) * 4;
    int*   histT     = (int*)p;                 p += (size_t)m * 4;
    int*   basea     = (int*)p;                 p += (size_t)(m + 1) * 4;
    int*   bsum      = (int*)p;                 p += (size_t)nbscan * 4;
    const size_t needed = (size_t)(p - ws);
    float* s = (float*)(ws + 1024);   // t1 dead after aggregation; reuse slot

    const int gemm_grid = (n + BM - 1) / BM;

    detect_idx64<<<1, 64, 0, stream>>>(E, flag);

    // layer 1 per-node transform (bf16 out)
    mlp_gemm<<<gemm_grid, 256, 0, stream>>>(x, W1, b1, nullptr, t1, nullptr, n, 0);

    if (ws_size >= needed && n <= 65536 && nbuck <= MAXBUCK) {
        // ---- coalesced counting partition + exact per-bucket CSR ----
        part_hist<<<NBLK, PTHREADS, 0, stream>>>(E, flag, histT, ne, n, nbuck);
        scang_blk<<<nbscan, 256, 0, stream>>>(histT, basea, bsum, m);
        scang_top<<<1, 256, 0, stream>>>(bsum, basea + m, nbscan);
        scang_add<<<nbscan, 256, 0, stream>>>(basea, bsum, m);
        part_scatter<<<NBLK, PTHREADS, 0, stream>>>(E, flag, basea, pe, ne, n, nbuck);
        bucket_csr<<<nbuck, 64, 0, stream>>>(pe, basea, offs, srcSorted, n, nbuck);

        // ---- aggregation without atomics ----
        gather_vec<<<2048, 256, 0, stream>>>(t1, offs, srcSorted, h1, n);

        // layer 2 fused with readout: s[m] = relu(h1[m]@W2+b2) . Wf
        mlp_gemm<<<gemm_grid, 256, 0, stream>>>(h1, W2, b2, Wf, nullptr, s, n, 1);

        gather_scalar<<<1024, 256, 0, stream>>>(s, offs, srcSorted, bf, out, n);
    } else {
        // ---- fallback: atomic scatter path ----
        (void)hipMemsetAsync(h1, 0, featB, stream);
        scatter_vec<<<8192, 256, 0, stream>>>(t1, E, flag, h1, ne, n);
        mlp_gemm<<<gemm_grid, 256, 0, stream>>>(h1, W2, b2, Wf, nullptr, s, n, 1);
        init_out<<<(n + 255) / 256, 256, 0, stream>>>(out, bf, n);
        scatter_scalar<<<2048, 256, 0, stream>>>(s, E, flag, out, ne, n);
    }
}